// Round 1
// baseline (25976.544 us; speedup 1.0000x reference)
//
#include <hip/hip_runtime.h>
#include <math.h>

#define N_  2048
#define T_  200
#define D_  16
#define H_  64
#define C2_ 128   // 2*H
#define BM  8

__device__ __forceinline__ float sig_(float x) {
    return __fdividef(1.0f, 1.0f + __expf(-x));
}
__device__ __forceinline__ float tanh_(float x) {
    float e = __expf(-2.0f * fabsf(x));
    float t = __fdividef(1.0f - e, 1.0f + e);
    return copysignf(t, x);
}

// Prologue: from h_init/c_init/x_0 compute X_0 = [h0@Wgh+bgh | c0@Wgc+bgc],
// and h_lstm_0 / c_lstm_0 (the LSTM cell output for step 0).
__global__ __launch_bounds__(64) void prologue_kernel(
    const float* __restrict__ xin, const float* __restrict__ h0,
    const float* __restrict__ c0,
    const float* __restrict__ Wgh, const float* __restrict__ bgh,
    const float* __restrict__ Wgc, const float* __restrict__ bgc,
    const float* __restrict__ K, const float* __restrict__ R,
    const float* __restrict__ bl,
    float* __restrict__ X, float* __restrict__ hl, float* __restrict__ cl)
{
    const int n = blockIdx.x;
    const int j = threadIdx.x;  // 0..63
    __shared__ float hs[H_], cs[H_], xs[D_];
    hs[j] = h0[n * H_ + j];
    cs[j] = c0[n * H_ + j];
    if (j < D_) xs[j] = xin[(size_t)n * T_ * D_ + j];  // t = 0
    __syncthreads();

    float xh = bgh[j], xc = bgc[j];
    for (int k = 0; k < H_; k++) {
        xh += hs[k] * Wgh[k * H_ + j];
        xc += cs[k] * Wgc[k * H_ + j];
    }
    X[n * C2_ + j]       = xh;
    X[n * C2_ + H_ + j]  = xc;

    float zi = bl[j], zf = bl[H_ + j], zg = bl[2 * H_ + j], zo = bl[3 * H_ + j];
    for (int d = 0; d < D_; d++) {
        float xv = xs[d];
        zi += xv * K[d * 256 + j];
        zf += xv * K[d * 256 + 64 + j];
        zg += xv * K[d * 256 + 128 + j];
        zo += xv * K[d * 256 + 192 + j];
    }
    for (int k = 0; k < H_; k++) {
        float hv = hs[k];
        zi += hv * R[k * 256 + j];
        zf += hv * R[k * 256 + 64 + j];
        zg += hv * R[k * 256 + 128 + j];
        zo += hv * R[k * 256 + 192 + j];
    }
    float clv = sig_(zf) * cs[j] + sig_(zi) * tanh_(zg);
    float hlv = sig_(zo) * tanh_(clv);
    cl[n * H_ + j] = clv;
    hl[n * H_ + j] = hlv;
}

// One step: G = tanh(A @ X) (the only cross-row op), then per-row epilogue:
// h_new/c_new -> outputs, then X_{t+1}, h_lstm_{t+1}, c_lstm_{t+1}.
__global__ __launch_bounds__(256) void step_kernel(
    const float* __restrict__ A,
    const float* __restrict__ Xc,   // [N][128] current X
    float* __restrict__ Xn,         // [N][128] next X
    float* __restrict__ hl,         // [N][64] h_lstm (in/out, own rows only)
    float* __restrict__ clm,        // [N][64] c_lstm (in/out, own rows only)
    const float* __restrict__ xin,  // inputs [N][T][D]
    const float* __restrict__ Whc, const float* __restrict__ Whp, const float* __restrict__ bh,
    const float* __restrict__ Wcc, const float* __restrict__ Wcp, const float* __restrict__ bc,
    const float* __restrict__ Wgh, const float* __restrict__ bgh,
    const float* __restrict__ Wgc, const float* __restrict__ bgc,
    const float* __restrict__ K, const float* __restrict__ R, const float* __restrict__ bl,
    float* __restrict__ oh, float* __restrict__ oc,  // [N][T][H] each
    int t)
{
    __shared__ float G[BM][C2_];          // tanh(A@X) rows: [.,0:64]=h_graph, [.,64:128]=c_graph
    __shared__ float HL[BM][H_], CL[BM][H_];
    __shared__ float HN[BM][H_], CN[BM][H_];
    __shared__ float XS[BM][D_];

    const int tid  = threadIdx.x;
    const int brow = blockIdx.x * BM;
    const int j    = tid & 127;     // output col 0..127
    const int rg   = tid >> 7;      // 0/1 -> rows rg*4 .. rg*4+3

    // stage h_lstm/c_lstm rows and x_{t+1}
    for (int idx = tid; idx < BM * H_; idx += 256) {
        int r = idx >> 6, c = idx & 63;
        HL[r][c] = hl[(brow + r) * H_ + c];
        CL[r][c] = clm[(brow + r) * H_ + c];
    }
    if (t + 1 < T_ && tid < BM * D_) {
        int r = tid >> 4, d = tid & 15;
        XS[r][d] = xin[(size_t)(brow + r) * T_ * D_ + (size_t)(t + 1) * D_ + d];
    }

    // ---- main GEMM: 4 rows x 1 col per thread ----
    const float* Ar = A + (size_t)(brow + rg * 4) * N_;
    float acc0 = 0.f, acc1 = 0.f, acc2 = 0.f, acc3 = 0.f;
    #pragma unroll 4
    for (int k = 0; k < N_; k += 4) {
        float4 a0 = *(const float4*)(Ar + k);
        float4 a1 = *(const float4*)(Ar + N_ + k);
        float4 a2 = *(const float4*)(Ar + 2 * N_ + k);
        float4 a3 = *(const float4*)(Ar + 3 * N_ + k);
        float x0 = Xc[(k + 0) * C2_ + j];
        float x1 = Xc[(k + 1) * C2_ + j];
        float x2 = Xc[(k + 2) * C2_ + j];
        float x3 = Xc[(k + 3) * C2_ + j];
        acc0 += a0.x * x0; acc1 += a1.x * x0; acc2 += a2.x * x0; acc3 += a3.x * x0;
        acc0 += a0.y * x1; acc1 += a1.y * x1; acc2 += a2.y * x1; acc3 += a3.y * x1;
        acc0 += a0.z * x2; acc1 += a1.z * x2; acc2 += a2.z * x2; acc3 += a3.z * x2;
        acc0 += a0.w * x3; acc1 += a1.w * x3; acc2 += a2.w * x3; acc3 += a3.w * x3;
    }
    G[rg * 4 + 0][j] = tanh_(acc0);
    G[rg * 4 + 1][j] = tanh_(acc1);
    G[rg * 4 + 2][j] = tanh_(acc2);
    G[rg * 4 + 3][j] = tanh_(acc3);
    __syncthreads();

    // ---- epilogue A: h_new / c_new (2 rows x 1 col per thread) ----
    {
        const int col = tid & 63;
        const int rr  = tid >> 6;   // 0..3 -> rows rr, rr+4
        float ah[2], ac[2];
        ah[0] = ah[1] = bh[col];
        ac[0] = ac[1] = bc[col];
        for (int k = 0; k < H_; k++) {
            float whc = Whc[k * H_ + col], whp = Whp[k * H_ + col];
            float wcc = Wcc[k * H_ + col], wcp = Wcp[k * H_ + col];
            #pragma unroll
            for (int p = 0; p < 2; p++) {
                int r = rr + p * 4;
                ah[p] += HL[r][k] * whc + G[r][k] * whp;
                ac[p] += CL[r][k] * wcc + G[r][H_ + k] * wcp;
            }
        }
        #pragma unroll
        for (int p = 0; p < 2; p++) {
            int r = rr + p * 4;
            float hnv = sig_(ah[p]), cnv = sig_(ac[p]);
            HN[r][col] = hnv;
            CN[r][col] = cnv;
            size_t o = (size_t)(brow + r) * T_ * H_ + (size_t)t * H_ + col;
            oh[o] = hnv;
            oc[o] = cnv;
        }
    }
    __syncthreads();

    if (t + 1 < T_) {
        // ---- epilogue B: X_{t+1} = [h_new@Wgh+bgh | c_new@Wgc+bgc] ----
        {
            float bias = (j < H_) ? bgh[j] : bgc[j - H_];
            const float* W = (j < H_) ? (Wgh + j) : (Wgc + (j - H_));
            const float (*S)[H_] = (j < H_) ? HN : CN;
            float acc[4];
            acc[0] = acc[1] = acc[2] = acc[3] = bias;
            for (int k = 0; k < H_; k++) {
                float w = W[k * H_];
                #pragma unroll
                for (int p = 0; p < 4; p++)
                    acc[p] += S[rg * 4 + p][k] * w;
            }
            #pragma unroll
            for (int p = 0; p < 4; p++)
                Xn[(brow + rg * 4 + p) * C2_ + j] = acc[p];
        }
        // ---- epilogue C: LSTM gates for step t+1 ----
        {
            const int col = tid & 63;
            const int rr  = tid >> 6;
            float z[2][4];
            #pragma unroll
            for (int p = 0; p < 2; p++) {
                z[p][0] = bl[col];       z[p][1] = bl[64 + col];
                z[p][2] = bl[128 + col]; z[p][3] = bl[192 + col];
            }
            for (int d = 0; d < D_; d++) {
                float k0 = K[d * 256 + col],       k1 = K[d * 256 + 64 + col];
                float k2 = K[d * 256 + 128 + col], k3 = K[d * 256 + 192 + col];
                #pragma unroll
                for (int p = 0; p < 2; p++) {
                    float xv = XS[rr + p * 4][d];
                    z[p][0] += xv * k0; z[p][1] += xv * k1;
                    z[p][2] += xv * k2; z[p][3] += xv * k3;
                }
            }
            for (int k = 0; k < H_; k++) {
                float r0 = R[k * 256 + col],       r1 = R[k * 256 + 64 + col];
                float r2 = R[k * 256 + 128 + col], r3 = R[k * 256 + 192 + col];
                #pragma unroll
                for (int p = 0; p < 2; p++) {
                    float hv = HN[rr + p * 4][k];
                    z[p][0] += hv * r0; z[p][1] += hv * r1;
                    z[p][2] += hv * r2; z[p][3] += hv * r3;
                }
            }
            #pragma unroll
            for (int p = 0; p < 2; p++) {
                int r = rr + p * 4;
                int row = brow + r;
                float clv = sig_(z[p][1]) * CN[r][col] + sig_(z[p][0]) * tanh_(z[p][2]);
                float hlv = sig_(z[p][3]) * tanh_(clv);
                clm[row * H_ + col] = clv;
                hl[row * H_ + col]  = hlv;
            }
        }
    }
}

extern "C" void kernel_launch(void* const* d_in, const int* in_sizes, int n_in,
                              void* d_out, int out_size, void* d_ws, size_t ws_size,
                              hipStream_t stream) {
    const float* xin = (const float*)d_in[0];
    const float* h0  = (const float*)d_in[1];
    const float* c0  = (const float*)d_in[2];
    const float* A   = (const float*)d_in[3];
    const float* Wgh = (const float*)d_in[4];
    const float* bgh = (const float*)d_in[5];
    const float* Wgc = (const float*)d_in[6];
    const float* bgc = (const float*)d_in[7];
    const float* Whc = (const float*)d_in[8];
    const float* Whp = (const float*)d_in[9];
    const float* bh  = (const float*)d_in[10];
    const float* Wcc = (const float*)d_in[11];
    const float* Wcp = (const float*)d_in[12];
    const float* bc  = (const float*)d_in[13];
    const float* K   = (const float*)d_in[14];
    const float* R   = (const float*)d_in[15];
    const float* bl  = (const float*)d_in[16];

    float* ws = (float*)d_ws;
    float* X0 = ws;
    float* X1 = X0 + (size_t)N_ * C2_;
    float* hl = X1 + (size_t)N_ * C2_;
    float* cl = hl + (size_t)N_ * H_;

    float* oh = (float*)d_out;
    float* oc = oh + (size_t)N_ * T_ * H_;

    prologue_kernel<<<N_, 64, 0, stream>>>(xin, h0, c0, Wgh, bgh, Wgc, bgc,
                                           K, R, bl, X0, hl, cl);
    for (int t = 0; t < T_; t++) {
        const float* Xc = (t & 1) ? X1 : X0;
        float*       Xn = (t & 1) ? X0 : X1;
        step_kernel<<<N_ / BM, 256, 0, stream>>>(A, Xc, Xn, hl, cl, xin,
                                                 Whc, Whp, bh, Wcc, Wcp, bc,
                                                 Wgh, bgh, Wgc, bgc, K, R, bl,
                                                 oh, oc, t);
    }
}

// Round 2
// 7697.673 us; speedup vs baseline: 3.3746x; 3.3746x over previous
//
#include <hip/hip_runtime.h>
#include <math.h>

#define N_  2048
#define T_  200
#define D_  16
#define H_  64
#define C2_ 128   // 2*H
#define BM  16
#define NTHR 512

typedef short bf16x8 __attribute__((ext_vector_type(8)));
typedef float f32x4 __attribute__((ext_vector_type(4)));

__device__ __forceinline__ float sig_(float x) {
    return __fdividef(1.0f, 1.0f + __expf(-x));
}
__device__ __forceinline__ float tanh_(float x) {
    float e = __expf(-2.0f * fabsf(x));
    float t = __fdividef(1.0f - e, 1.0f + e);
    return copysignf(t, x);
}
__device__ __forceinline__ unsigned short f2bf(float f) {
    unsigned u = __float_as_uint(f);
    u = (u + 0x7FFFu + ((u >> 16) & 1u)) >> 16;   // round-to-nearest-even
    return (unsigned short)u;
}

// ---- A (fp32) -> A (bf16), once per launch ----
__global__ __launch_bounds__(256) void convert_A_kernel(
    const float* __restrict__ A, unsigned short* __restrict__ Abf)
{
    size_t i = ((size_t)blockIdx.x * 256 + threadIdx.x) * 4;
    float4 v = *(const float4*)(A + i);
    ushort4 o;
    o.x = f2bf(v.x); o.y = f2bf(v.y); o.z = f2bf(v.z); o.w = f2bf(v.w);
    *(ushort4*)(Abf + i) = o;
}

// ---- Prologue: X_0^T (bf16), h_lstm_0, c_lstm_0 ----
__global__ __launch_bounds__(64) void prologue_kernel(
    const float* __restrict__ xin, const float* __restrict__ h0,
    const float* __restrict__ c0,
    const float* __restrict__ Wgh, const float* __restrict__ bgh,
    const float* __restrict__ Wgc, const float* __restrict__ bgc,
    const float* __restrict__ K, const float* __restrict__ R,
    const float* __restrict__ bl,
    unsigned short* __restrict__ Xt,   // [128][2048] bf16, transposed
    float* __restrict__ hl, float* __restrict__ cl)
{
    const int n = blockIdx.x;
    const int j = threadIdx.x;  // 0..63
    __shared__ float hs[H_], cs[H_], xs[D_];
    hs[j] = h0[n * H_ + j];
    cs[j] = c0[n * H_ + j];
    if (j < D_) xs[j] = xin[(size_t)n * T_ * D_ + j];  // t = 0
    __syncthreads();

    float xh = bgh[j], xc = bgc[j];
    for (int k = 0; k < H_; k++) {
        xh += hs[k] * Wgh[k * H_ + j];
        xc += cs[k] * Wgc[k * H_ + j];
    }
    Xt[(size_t)j * N_ + n]        = f2bf(xh);
    Xt[(size_t)(H_ + j) * N_ + n] = f2bf(xc);

    float zi = bl[j], zf = bl[H_ + j], zg = bl[2 * H_ + j], zo = bl[3 * H_ + j];
    for (int d = 0; d < D_; d++) {
        float xv = xs[d];
        zi += xv * K[d * 256 + j];
        zf += xv * K[d * 256 + 64 + j];
        zg += xv * K[d * 256 + 128 + j];
        zo += xv * K[d * 256 + 192 + j];
    }
    for (int k = 0; k < H_; k++) {
        float hv = hs[k];
        zi += hv * R[k * 256 + j];
        zf += hv * R[k * 256 + 64 + j];
        zg += hv * R[k * 256 + 128 + j];
        zo += hv * R[k * 256 + 192 + j];
    }
    float clv = sig_(zf) * cs[j] + sig_(zi) * tanh_(zg);
    float hlv = sig_(zo) * tanh_(clv);
    cl[n * H_ + j] = clv;
    hl[n * H_ + j] = hlv;
}

// ---- One step: G = tanh(A@X) via bf16 MFMA, then per-row epilogues ----
__global__ __launch_bounds__(NTHR) void step_kernel(
    const unsigned short* __restrict__ Abf,   // [2048][2048] bf16
    const unsigned short* __restrict__ Xct,   // [128][2048] bf16 (X^T)
    unsigned short* __restrict__ Xnt,         // [128][2048] bf16 (X_{t+1}^T)
    float* __restrict__ hl, float* __restrict__ clm,
    const float* __restrict__ xin,
    const float* __restrict__ Whc, const float* __restrict__ Whp, const float* __restrict__ bh,
    const float* __restrict__ Wcc, const float* __restrict__ Wcp, const float* __restrict__ bc,
    const float* __restrict__ Wgh, const float* __restrict__ bgh,
    const float* __restrict__ Wgc, const float* __restrict__ bgc,
    const float* __restrict__ K, const float* __restrict__ R, const float* __restrict__ bl,
    float* __restrict__ oh, float* __restrict__ oc,
    int t)
{
    __shared__ float part[2][BM][C2_];   // 16 KB partials; reused as XBf[128][17]
    __shared__ float G[BM][C2_];         // tanh(A@X): [.,0:64]=h_graph, [.,64:128]=c_graph
    __shared__ float HL[BM][H_], CL[BM][H_], HN[BM][H_], CN[BM][H_];
    __shared__ float XS[BM][D_];

    const int tid  = threadIdx.x;
    const int brow = blockIdx.x * BM;
    const int wave = tid >> 6;
    const int lane = tid & 63;

    for (int idx = tid; idx < BM * H_; idx += NTHR) {
        int r = idx >> 6, c = idx & 63;
        HL[r][c] = hl[(brow + r) * H_ + c];
        CL[r][c] = clm[(brow + r) * H_ + c];
    }
    if (t + 1 < T_ && tid < BM * D_) {
        int r = tid >> 4, d = tid & 15;
        XS[r][d] = xin[(size_t)(brow + r) * T_ * D_ + (size_t)(t + 1) * D_ + d];
    }

    // ---- GEMM: wave w -> col-tile (w&3)*32, K-half (w>>2)*1024 ----
    {
        const int ct = (wave & 3) * 32;
        const int kh = (wave >> 2) * 1024;
        const int fr = lane & 15;   // A-row / B-col within tile
        const int kg = lane >> 4;   // k-group (8 contiguous k each)
        const unsigned short* Ap  = Abf + (size_t)(brow + fr) * N_ + kh + kg * 8;
        const unsigned short* Bp0 = Xct + (size_t)(ct + fr) * N_ + kh + kg * 8;
        const unsigned short* Bp1 = Bp0 + (size_t)16 * N_;
        f32x4 acc0 = {0.f, 0.f, 0.f, 0.f}, acc1 = {0.f, 0.f, 0.f, 0.f};
        #pragma unroll 8
        for (int kk = 0; kk < 32; kk++) {
            bf16x8 a  = *(const bf16x8*)(Ap  + kk * 32);
            bf16x8 b0 = *(const bf16x8*)(Bp0 + kk * 32);
            bf16x8 b1 = *(const bf16x8*)(Bp1 + kk * 32);
            acc0 = __builtin_amdgcn_mfma_f32_16x16x32_bf16(a, b0, acc0, 0, 0, 0);
            acc1 = __builtin_amdgcn_mfma_f32_16x16x32_bf16(a, b1, acc1, 0, 0, 0);
        }
        const int g  = wave >> 2;
        const int rb = kg * 4;      // C/D: row = (lane>>4)*4 + reg  (verified layout)
        #pragma unroll
        for (int r = 0; r < 4; r++) {
            part[g][rb + r][ct + fr]      = acc0[r];
            part[g][rb + r][ct + 16 + fr] = acc1[r];
        }
    }
    __syncthreads();
    for (int idx = tid; idx < BM * C2_; idx += NTHR) {
        int r = idx >> 7, c = idx & 127;
        G[r][c] = tanh_(part[0][r][c] + part[1][r][c]);
    }
    __syncthreads();

    // ---- epilogue A: h_new / c_new ----
    {
        const int col = tid & 63;
        const int rr  = tid >> 6;   // 0..7 -> rows rr, rr+8
        float ah[2], ac[2];
        ah[0] = ah[1] = bh[col];
        ac[0] = ac[1] = bc[col];
        for (int k = 0; k < H_; k++) {
            float whc = Whc[k * H_ + col], whp = Whp[k * H_ + col];
            float wcc = Wcc[k * H_ + col], wcp = Wcp[k * H_ + col];
            #pragma unroll
            for (int p = 0; p < 2; p++) {
                int r = rr + p * 8;
                ah[p] += HL[r][k] * whc + G[r][k] * whp;
                ac[p] += CL[r][k] * wcc + G[r][H_ + k] * wcp;
            }
        }
        #pragma unroll
        for (int p = 0; p < 2; p++) {
            int r = rr + p * 8;
            float hnv = sig_(ah[p]), cnv = sig_(ac[p]);
            HN[r][col] = hnv;
            CN[r][col] = cnv;
            size_t o = (size_t)(brow + r) * T_ * H_ + (size_t)t * H_ + col;
            oh[o] = hnv;
            oc[o] = cnv;
        }
    }
    __syncthreads();

    if (t + 1 < T_) {
        float* XBf = (float*)part;   // [128][17] scratch for transposed store
        // ---- epilogue B: X_{t+1} = [h_new@Wgh+bgh | c_new@Wgc+bgc] ----
        {
            const int j  = tid & 127;
            const int rg = tid >> 7;  // 0..3 -> rows rg*4 .. rg*4+3
            float bias = (j < H_) ? bgh[j] : bgc[j - H_];
            const float* W = (j < H_) ? (Wgh + j) : (Wgc + (j - H_));
            const float (*S)[H_] = (j < H_) ? HN : CN;
            float acc[4];
            acc[0] = acc[1] = acc[2] = acc[3] = bias;
            for (int k = 0; k < H_; k++) {
                float w = W[(size_t)k * H_];
                #pragma unroll
                for (int p = 0; p < 4; p++)
                    acc[p] += S[rg * 4 + p][k] * w;
            }
            #pragma unroll
            for (int p = 0; p < 4; p++)
                XBf[j * 17 + rg * 4 + p] = acc[p];
        }
        __syncthreads();
        // transposed coalesced-ish bf16 store of X_{t+1}^T
        {
            const int j  = tid >> 2;        // 0..127
            const int rb = (tid & 3) * 4;   // 0,4,8,12
            ushort4 o;
            o.x = f2bf(XBf[j * 17 + rb + 0]);
            o.y = f2bf(XBf[j * 17 + rb + 1]);
            o.z = f2bf(XBf[j * 17 + rb + 2]);
            o.w = f2bf(XBf[j * 17 + rb + 3]);
            *(ushort4*)(Xnt + (size_t)j * N_ + brow + rb) = o;
        }
        // ---- epilogue C: LSTM gates for step t+1 ----
        {
            const int col = tid & 63;
            const int rr  = tid >> 6;   // 0..7 -> rows rr, rr+8
            float z[2][4];
            #pragma unroll
            for (int p = 0; p < 2; p++) {
                z[p][0] = bl[col];       z[p][1] = bl[64 + col];
                z[p][2] = bl[128 + col]; z[p][3] = bl[192 + col];
            }
            for (int d = 0; d < D_; d++) {
                float k0 = K[d * 256 + col],       k1 = K[d * 256 + 64 + col];
                float k2 = K[d * 256 + 128 + col], k3 = K[d * 256 + 192 + col];
                #pragma unroll
                for (int p = 0; p < 2; p++) {
                    float xv = XS[rr + p * 8][d];
                    z[p][0] += xv * k0; z[p][1] += xv * k1;
                    z[p][2] += xv * k2; z[p][3] += xv * k3;
                }
            }
            for (int k = 0; k < H_; k++) {
                float r0 = R[k * 256 + col],       r1 = R[k * 256 + 64 + col];
                float r2 = R[k * 256 + 128 + col], r3 = R[k * 256 + 192 + col];
                #pragma unroll
                for (int p = 0; p < 2; p++) {
                    float hv = HN[rr + p * 8][k];
                    z[p][0] += hv * r0; z[p][1] += hv * r1;
                    z[p][2] += hv * r2; z[p][3] += hv * r3;
                }
            }
            #pragma unroll
            for (int p = 0; p < 2; p++) {
                int r = rr + p * 8;
                int row = brow + r;
                float clv = sig_(z[p][1]) * CN[r][col] + sig_(z[p][0]) * tanh_(z[p][2]);
                float hlv = sig_(z[p][3]) * tanh_(clv);
                clm[row * H_ + col] = clv;
                hl[row * H_ + col]  = hlv;
            }
        }
    }
}

extern "C" void kernel_launch(void* const* d_in, const int* in_sizes, int n_in,
                              void* d_out, int out_size, void* d_ws, size_t ws_size,
                              hipStream_t stream) {
    const float* xin = (const float*)d_in[0];
    const float* h0  = (const float*)d_in[1];
    const float* c0  = (const float*)d_in[2];
    const float* A   = (const float*)d_in[3];
    const float* Wgh = (const float*)d_in[4];
    const float* bgh = (const float*)d_in[5];
    const float* Wgc = (const float*)d_in[6];
    const float* bgc = (const float*)d_in[7];
    const float* Whc = (const float*)d_in[8];
    const float* Whp = (const float*)d_in[9];
    const float* bh  = (const float*)d_in[10];
    const float* Wcc = (const float*)d_in[11];
    const float* Wcp = (const float*)d_in[12];
    const float* bc  = (const float*)d_in[13];
    const float* K   = (const float*)d_in[14];
    const float* R   = (const float*)d_in[15];
    const float* bl  = (const float*)d_in[16];

    char* w = (char*)d_ws;
    unsigned short* Abf = (unsigned short*)w;  w += (size_t)N_ * N_ * 2;       // 8 MB
    unsigned short* Xt0 = (unsigned short*)w;  w += (size_t)C2_ * N_ * 2;      // 512 KB
    unsigned short* Xt1 = (unsigned short*)w;  w += (size_t)C2_ * N_ * 2;      // 512 KB
    float* hl = (float*)w;  w += (size_t)N_ * H_ * 4;                          // 512 KB
    float* cl = (float*)w;  w += (size_t)N_ * H_ * 4;                          // 512 KB

    float* oh = (float*)d_out;
    float* oc = oh + (size_t)N_ * T_ * H_;

    convert_A_kernel<<<(N_ * N_) / (256 * 4), 256, 0, stream>>>(A, Abf);
    prologue_kernel<<<N_, 64, 0, stream>>>(xin, h0, c0, Wgh, bgh, Wgc, bgc,
                                           K, R, bl, Xt0, hl, cl);
    for (int t = 0; t < T_; t++) {
        const unsigned short* Xc = (t & 1) ? Xt1 : Xt0;
        unsigned short*       Xn = (t & 1) ? Xt0 : Xt1;
        step_kernel<<<N_ / BM, NTHR, 0, stream>>>(Abf, Xc, Xn, hl, cl, xin,
                                                  Whc, Whp, bh, Wcc, Wcp, bc,
                                                  Wgh, bgh, Wgc, bgc, K, R, bl,
                                                  oh, oc, t);
    }
}

// Round 3
// 7174.938 us; speedup vs baseline: 3.6205x; 1.0729x over previous
//
#include <hip/hip_runtime.h>
#include <math.h>

#define N_  2048
#define T_  200
#define D_  16
#define H_  64
#define C2_ 128   // 2*H
#define BM  16
#define NTHR 1024

typedef unsigned short ushort_t;
typedef short bf16x8 __attribute__((ext_vector_type(8)));
typedef float f32x4 __attribute__((ext_vector_type(4)));

// ---- weight blob layout (ushort offsets) ----
#define W_HC 0        // W_h_cur^T  [64][64]  swz8
#define W_HP 4096     // W_h_prev^T [64][64]  swz8
#define W_CC 8192     // W_c_cur^T  [64][64]  swz8
#define W_CP 12288    // W_c_prev^T [64][64]  swz8
#define W_G  16384    // [Wgh^T ; Wgc^T] [128][64] swz8
#define W_R  24576    // R^T [256][64] swz8
#define W_K  40960    // K^T [256][16] swz2
#define W_USH 45056   // total bf16 ushorts; then 512 fp32 biases
#define BLOB_BYTES 92160   // 90 KB = 90 x 1KB stage issues

__device__ __forceinline__ float sig_(float x) {
    return __fdividef(1.0f, 1.0f + __expf(-x));
}
__device__ __forceinline__ float tanh_(float x) {
    float e = __expf(-2.0f * fabsf(x));
    float t = __fdividef(1.0f - e, 1.0f + e);
    return copysignf(t, x);
}
__device__ __forceinline__ ushort_t f2bf(float f) {
    unsigned u = __float_as_uint(f);
    u = (u + 0x7FFFu + ((u >> 16) & 1u)) >> 16;
    return (ushort_t)u;
}
__device__ __forceinline__ float blo(unsigned u){ return __uint_as_float(u << 16); }
__device__ __forceinline__ float bhi(unsigned u){ return __uint_as_float(u & 0xFFFF0000u); }

__device__ __forceinline__ void gload16(const void* g, void* l) {
    __builtin_amdgcn_global_load_lds(
        (const __attribute__((address_space(1))) unsigned int*)g,
        (__attribute__((address_space(3))) unsigned int*)l, 16, 0, 0);
}

// ---- A (fp32) -> A (bf16) ----
__global__ __launch_bounds__(256) void convert_A_kernel(
    const float* __restrict__ A, ushort_t* __restrict__ Abf)
{
    size_t i = ((size_t)blockIdx.x * 256 + threadIdx.x) * 4;
    float4 v = *(const float4*)(A + i);
    ushort4 o;
    o.x = f2bf(v.x); o.y = f2bf(v.y); o.z = f2bf(v.z); o.w = f2bf(v.w);
    *(ushort4*)(Abf + i) = o;
}

// ---- pack weights: bf16, transposed, XOR-swizzled 16B chunks ----
__global__ __launch_bounds__(256) void convert_W_kernel(
    const float* __restrict__ Whc, const float* __restrict__ Whp,
    const float* __restrict__ Wcc, const float* __restrict__ Wcp,
    const float* __restrict__ Wgh, const float* __restrict__ Wgc,
    const float* __restrict__ R,   const float* __restrict__ Kw,
    const float* __restrict__ bh,  const float* __restrict__ bc,
    const float* __restrict__ bgh, const float* __restrict__ bgc,
    const float* __restrict__ bl,
    ushort_t* __restrict__ blob)
{
    const int stride = gridDim.x * 256;
    const int gid = blockIdx.x * 256 + threadIdx.x;
    for (int idx = gid; idx < 4096; idx += stride) {       // [64][64] mats, idx = k*64+c
        int k = idx >> 6, c = idx & 63;
        int dst = c * 64 + ((((k >> 3) ^ c) & 7) << 3) + (k & 7);
        blob[W_HC + dst] = f2bf(Whc[idx]);
        blob[W_HP + dst] = f2bf(Whp[idx]);
        blob[W_CC + dst] = f2bf(Wcc[idx]);
        blob[W_CP + dst] = f2bf(Wcp[idx]);
        blob[W_G + dst]        = f2bf(Wgh[idx]);   // row j = c
        blob[W_G + 4096 + dst] = f2bf(Wgc[idx]);   // row j = 64+c (same swz: j&7==c&7)
    }
    for (int idx = gid; idx < 16384; idx += stride) {      // R [64][256], idx = k*256+gc
        int k = idx >> 8, gc = idx & 255;
        int dst = gc * 64 + ((((k >> 3) ^ gc) & 7) << 3) + (k & 7);
        blob[W_R + dst] = f2bf(R[idx]);
    }
    for (int idx = gid; idx < 4096; idx += stride) {       // Kw [16][256], idx = d*256+gc
        int d = idx >> 8, gc = idx & 255;
        int dst = gc * 16 + ((((d >> 3) ^ gc) & 1) << 3) + (d & 7);
        blob[W_K + dst] = f2bf(Kw[idx]);
    }
    float* bf = (float*)(blob + W_USH);
    if (gid < 64) { bf[gid] = bh[gid]; bf[64+gid] = bc[gid]; bf[128+gid] = bgh[gid]; bf[192+gid] = bgc[gid]; }
    if (gid < 256) bf[256 + gid] = bl[gid];
}

// ---- Prologue: X_0^T (bf16), h_lstm_0, c_lstm_0 ----
__global__ __launch_bounds__(64) void prologue_kernel(
    const float* __restrict__ xin, const float* __restrict__ h0,
    const float* __restrict__ c0,
    const float* __restrict__ Wgh, const float* __restrict__ bgh,
    const float* __restrict__ Wgc, const float* __restrict__ bgc,
    const float* __restrict__ K, const float* __restrict__ R,
    const float* __restrict__ bl,
    ushort_t* __restrict__ Xt, float* __restrict__ hl, float* __restrict__ cl)
{
    const int n = blockIdx.x;
    const int j = threadIdx.x;
    __shared__ float hs[H_], cs[H_], xs[D_];
    hs[j] = h0[n * H_ + j];
    cs[j] = c0[n * H_ + j];
    if (j < D_) xs[j] = xin[(size_t)n * T_ * D_ + j];
    __syncthreads();

    float xh = bgh[j], xc = bgc[j];
    for (int k = 0; k < H_; k++) {
        xh += hs[k] * Wgh[k * H_ + j];
        xc += cs[k] * Wgc[k * H_ + j];
    }
    Xt[(size_t)j * N_ + n]        = f2bf(xh);
    Xt[(size_t)(H_ + j) * N_ + n] = f2bf(xc);

    float zi = bl[j], zf = bl[H_ + j], zg = bl[2 * H_ + j], zo = bl[3 * H_ + j];
    for (int d = 0; d < D_; d++) {
        float xv = xs[d];
        zi += xv * K[d * 256 + j];
        zf += xv * K[d * 256 + 64 + j];
        zg += xv * K[d * 256 + 128 + j];
        zo += xv * K[d * 256 + 192 + j];
    }
    for (int k = 0; k < H_; k++) {
        float hv = hs[k];
        zi += hv * R[k * 256 + j];
        zf += hv * R[k * 256 + 64 + j];
        zg += hv * R[k * 256 + 128 + j];
        zo += hv * R[k * 256 + 192 + j];
    }
    float clv = sig_(zf) * cs[j] + sig_(zi) * tanh_(zg);
    float hlv = sig_(zo) * tanh_(clv);
    cl[n * H_ + j] = clv;
    hl[n * H_ + j] = hlv;
}

// ---- One step ----
__global__ __launch_bounds__(NTHR, 4) void step_kernel(
    const ushort_t* __restrict__ Abf,
    const ushort_t* __restrict__ Xct,
    ushort_t* __restrict__ Xnt,
    float* __restrict__ hl, float* __restrict__ clm,
    const float* __restrict__ xin,
    const ushort_t* __restrict__ Wblob,
    float* __restrict__ oh, float* __restrict__ oc,
    int t)
{
    __shared__ __align__(16) ushort_t WL[46080];     // 90 KB: bf16 weights + fp32 biases
    __shared__ __align__(16) float HLs[BM * H_], CLs[BM * H_];
    __shared__ __align__(16) float XSs[BM * D_];
    __shared__ __align__(16) float part[4 * BM * C2_];   // 32 KB; aliased as XBf later
    __shared__ __align__(16) float Gs[BM * C2_];
    __shared__ __align__(16) float HNs[BM * H_], CNs[BM * H_];

    const int tid  = threadIdx.x;
    const int brow = blockIdx.x * BM;
    const int wave = tid >> 6;
    const int lane = tid & 63;

    // ---- stage weights + state into LDS (async, drains at first barrier) ----
    {
        const char* gsrc = (const char*)Wblob;
        char* lbase = (char*)WL;
        for (int i = wave; i < 90; i += 16)
            gload16(gsrc + i * 1024 + lane * 16, lbase + i * 1024);
        if (wave >= 8 && wave < 12) {
            int i = wave - 8;
            gload16((const char*)(hl + (size_t)brow * H_) + i * 1024 + lane * 16,
                    (char*)HLs + i * 1024);
        }
        if (wave >= 12) {
            int i = wave - 12;
            gload16((const char*)(clm + (size_t)brow * H_) + i * 1024 + lane * 16,
                    (char*)CLs + i * 1024);
        }
        if (t + 1 < T_ && wave == 0) {
            const float* g = xin + (size_t)(brow + (lane >> 2)) * (T_ * D_)
                                 + (size_t)(t + 1) * D_ + (lane & 3) * 4;
            gload16(g, (char*)XSs);
        }
    }

    // ---- GEMM: 16 waves = 4 col-tiles x 4 k-quarters ----
    {
        const int ct = (wave & 3) * 32;
        const int kq = (wave >> 2) * 512;
        const int fr = lane & 15;
        const int kg = lane >> 4;
        const ushort_t* Ap  = Abf + (size_t)(brow + fr) * N_ + kq + kg * 8;
        const ushort_t* Bp0 = Xct + (size_t)(ct + fr) * N_ + kq + kg * 8;
        const ushort_t* Bp1 = Bp0 + (size_t)16 * N_;
        f32x4 acc0 = {0.f, 0.f, 0.f, 0.f}, acc1 = {0.f, 0.f, 0.f, 0.f};
        #pragma unroll 4
        for (int kk = 0; kk < 16; kk++) {
            bf16x8 a  = *(const bf16x8*)(Ap  + kk * 32);
            bf16x8 b0 = *(const bf16x8*)(Bp0 + kk * 32);
            bf16x8 b1 = *(const bf16x8*)(Bp1 + kk * 32);
            acc0 = __builtin_amdgcn_mfma_f32_16x16x32_bf16(a, b0, acc0, 0, 0, 0);
            acc1 = __builtin_amdgcn_mfma_f32_16x16x32_bf16(a, b1, acc1, 0, 0, 0);
        }
        float* pp = &part[(wave >> 2) * (BM * C2_) + ct];
        const int rb = kg * 4;
        #pragma unroll
        for (int r = 0; r < 4; r++) {
            pp[(rb + r) * C2_ + fr]      = acc0[r];
            pp[(rb + r) * C2_ + 16 + fr] = acc1[r];
        }
    }
    __syncthreads();   // part complete + all staging drained (vmcnt 0 before barrier)

    // ---- reduce 4 k-partials + tanh -> G ----
    {
        #pragma unroll
        for (int p = 0; p < 2; p++) {
            int i = tid + p * 1024;
            Gs[i] = tanh_(part[i] + part[BM*C2_ + i] + part[2*BM*C2_ + i] + part[3*BM*C2_ + i]);
        }
    }
    __syncthreads();

    const float* BL = (const float*)(WL + W_USH);

    // ---- epilogue A: h_new / c_new ----
    {
        const int c = tid & 63;
        const int r = tid >> 6;
        const int swz = c & 7;
        float ah = BL[c], ac = BL[64 + c];
        #pragma unroll
        for (int kk = 0; kk < 8; kk++) {
            const int pc = ((kk ^ swz) << 3);
            uint4 w1 = *(const uint4*)&WL[W_HC + c * 64 + pc];
            uint4 w2 = *(const uint4*)&WL[W_HP + c * 64 + pc];
            uint4 w3 = *(const uint4*)&WL[W_CC + c * 64 + pc];
            uint4 w4 = *(const uint4*)&WL[W_CP + c * 64 + pc];
            const float* hb = &HLs[r * 64 + kk * 8];
            const float* gh = &Gs[r * 128 + kk * 8];
            const float* cb = &CLs[r * 64 + kk * 8];
            const float* gc = &Gs[r * 128 + 64 + kk * 8];
            const unsigned* u1 = (const unsigned*)&w1;
            const unsigned* u2 = (const unsigned*)&w2;
            const unsigned* u3 = (const unsigned*)&w3;
            const unsigned* u4 = (const unsigned*)&w4;
            #pragma unroll
            for (int q = 0; q < 4; q++) {
                ah += blo(u1[q]) * hb[2*q] + bhi(u1[q]) * hb[2*q+1];
                ah += blo(u2[q]) * gh[2*q] + bhi(u2[q]) * gh[2*q+1];
                ac += blo(u3[q]) * cb[2*q] + bhi(u3[q]) * cb[2*q+1];
                ac += blo(u4[q]) * gc[2*q] + bhi(u4[q]) * gc[2*q+1];
            }
        }
        float hnv = sig_(ah), cnv = sig_(ac);
        HNs[r * 64 + c] = hnv;
        CNs[r * 64 + c] = cnv;
        size_t o = (size_t)(brow + r) * (T_ * H_) + (size_t)t * H_ + c;
        oh[o] = hnv;
        oc[o] = cnv;
    }
    __syncthreads();

    if (t + 1 < T_) {
        float* XBf = part;   // [128][17] scratch (part dead after reduce)
        // ---- epilogue B: X_{t+1} ----
        {
            const int j  = tid & 127;
            const int rp = tid >> 7;   // rows rp, rp+8
            const int jj = j & 63;
            const float* S = (j < 64) ? HNs : CNs;
            float bias = (j < 64) ? BL[128 + jj] : BL[192 + jj];
            float a0 = bias, a1 = bias;
            const int swz = j & 7;
            #pragma unroll
            for (int kk = 0; kk < 8; kk++) {
                const int pc = ((kk ^ swz) << 3);
                uint4 w = *(const uint4*)&WL[W_G + j * 64 + pc];
                const unsigned* u = (const unsigned*)&w;
                const float* s0 = &S[rp * 64 + kk * 8];
                const float* s1 = &S[(rp + 8) * 64 + kk * 8];
                #pragma unroll
                for (int q = 0; q < 4; q++) {
                    a0 += blo(u[q]) * s0[2*q] + bhi(u[q]) * s0[2*q+1];
                    a1 += blo(u[q]) * s1[2*q] + bhi(u[q]) * s1[2*q+1];
                }
            }
            XBf[j * 17 + rp]     = a0;
            XBf[j * 17 + rp + 8] = a1;
        }
        // ---- epilogue C: LSTM gates for t+1 ----
        float z[4];
        {
            const int c = tid & 63;
            const int r = tid >> 6;
            #pragma unroll
            for (int g = 0; g < 4; g++) z[g] = BL[256 + g * 64 + c];
            const int swz1 = c & 1, swz = c & 7;
            #pragma unroll
            for (int g = 0; g < 4; g++) {
                const ushort_t* Krow = &WL[W_K + (g * 64 + c) * 16];
                #pragma unroll
                for (int dd = 0; dd < 2; dd++) {
                    const int pc = ((dd ^ swz1) << 3);
                    uint4 w = *(const uint4*)&Krow[pc];
                    const unsigned* u = (const unsigned*)&w;
                    const float* xb = &XSs[r * 16 + dd * 8];
                    #pragma unroll
                    for (int q = 0; q < 4; q++)
                        z[g] += blo(u[q]) * xb[2*q] + bhi(u[q]) * xb[2*q+1];
                }
                const ushort_t* Rrow = &WL[W_R + (g * 64 + c) * 64];
                #pragma unroll
                for (int kk = 0; kk < 8; kk++) {
                    const int pc = ((kk ^ swz) << 3);
                    uint4 w = *(const uint4*)&Rrow[pc];
                    const unsigned* u = (const unsigned*)&w;
                    const float* hb = &HNs[r * 64 + kk * 8];
                    #pragma unroll
                    for (int q = 0; q < 4; q++)
                        z[g] += blo(u[q]) * hb[2*q] + bhi(u[q]) * hb[2*q+1];
                }
            }
            float clv = sig_(z[1]) * CNs[r * 64 + c] + sig_(z[0]) * tanh_(z[2]);
            float hlv = sig_(z[3]) * tanh_(clv);
            clm[(size_t)(brow + r) * H_ + c] = clv;
            hl[(size_t)(brow + r) * H_ + c]  = hlv;
        }
        __syncthreads();
        // ---- store X_{t+1}^T bf16 ----
        if (tid < 512) {
            const float* XBc = part;
            const int j  = tid >> 2;
            const int rb = (tid & 3) * 4;
            ushort4 o;
            o.x = f2bf(XBc[j * 17 + rb + 0]);
            o.y = f2bf(XBc[j * 17 + rb + 1]);
            o.z = f2bf(XBc[j * 17 + rb + 2]);
            o.w = f2bf(XBc[j * 17 + rb + 3]);
            *(ushort4*)(Xnt + (size_t)j * N_ + brow + rb) = o;
        }
    }
}

extern "C" void kernel_launch(void* const* d_in, const int* in_sizes, int n_in,
                              void* d_out, int out_size, void* d_ws, size_t ws_size,
                              hipStream_t stream) {
    const float* xin = (const float*)d_in[0];
    const float* h0  = (const float*)d_in[1];
    const float* c0  = (const float*)d_in[2];
    const float* A   = (const float*)d_in[3];
    const float* Wgh = (const float*)d_in[4];
    const float* bgh = (const float*)d_in[5];
    const float* Wgc = (const float*)d_in[6];
    const float* bgc = (const float*)d_in[7];
    const float* Whc = (const float*)d_in[8];
    const float* Whp = (const float*)d_in[9];
    const float* bh  = (const float*)d_in[10];
    const float* Wcc = (const float*)d_in[11];
    const float* Wcp = (const float*)d_in[12];
    const float* bc  = (const float*)d_in[13];
    const float* K   = (const float*)d_in[14];
    const float* R   = (const float*)d_in[15];
    const float* bl  = (const float*)d_in[16];

    char* w = (char*)d_ws;
    ushort_t* Abf  = (ushort_t*)w;  w += (size_t)N_ * N_ * 2;
    ushort_t* Xt0  = (ushort_t*)w;  w += (size_t)C2_ * N_ * 2;
    ushort_t* Xt1  = (ushort_t*)w;  w += (size_t)C2_ * N_ * 2;
    float* hl      = (float*)w;     w += (size_t)N_ * H_ * 4;
    float* cl      = (float*)w;     w += (size_t)N_ * H_ * 4;
    ushort_t* blob = (ushort_t*)w;  w += BLOB_BYTES;

    float* oh = (float*)d_out;
    float* oc = oh + (size_t)N_ * T_ * H_;

    convert_A_kernel<<<(N_ * N_) / (256 * 4), 256, 0, stream>>>(A, Abf);
    convert_W_kernel<<<16, 256, 0, stream>>>(Whc, Whp, Wcc, Wcp, Wgh, Wgc, R, K,
                                             bh, bc, bgh, bgc, bl, blob);
    prologue_kernel<<<N_, 64, 0, stream>>>(xin, h0, c0, Wgh, bgh, Wgc, bgc,
                                           K, R, bl, Xt0, hl, cl);
    for (int t = 0; t < T_; t++) {
        const ushort_t* Xc = (t & 1) ? Xt1 : Xt0;
        ushort_t*       Xn = (t & 1) ? Xt0 : Xt1;
        step_kernel<<<N_ / BM, NTHR, 0, stream>>>(Abf, Xc, Xn, hl, cl, xin,
                                                  blob, oh, oc, t);
    }
}